// Round 1
// baseline (716.959 us; speedup 1.0000x reference)
//
#include <hip/hip_runtime.h>
#include <hip/hip_bf16.h>

// ---------------------------------------------------------------------------
// Model: B=8 S=1024 D=256 H=8 DK=64 DV=256; LB=LF=32, CUT=128, VOCAB=240
// out = head( attn_causal( concat( attn_local(x), attn_global(x) ) ) )
// All matmuls via mfma_f32_16x16x32_bf16 (bf16 in, f32 acc).
// ---------------------------------------------------------------------------

typedef __bf16 bf16_t;
typedef __bf16 bf16x8 __attribute__((ext_vector_type(8)));
typedef float f32x4 __attribute__((ext_vector_type(4)));

__device__ __forceinline__ f32x4 mfma16(bf16x8 a, bf16x8 b, f32x4 c) {
  return __builtin_amdgcn_mfma_f32_16x16x32_bf16(a, b, c, 0, 0, 0);
}

#define GLL16(GP, LP)                                                          \
  __builtin_amdgcn_global_load_lds(                                            \
      (const __attribute__((address_space(1))) void*)(GP),                     \
      (__attribute__((address_space(3))) void*)(LP), 16, 0, 0)

__device__ __forceinline__ int imin(int a, int b) { return a < b ? a : b; }
__device__ __forceinline__ int imax(int a, int b) { return a > b ? a : b; }

// ---- weight transpose + cast: Wt[n*K + k] = (bf16) W[k*N + n] --------------
__global__ void wcast_k(const float* __restrict__ W, bf16_t* __restrict__ Wt,
                        int K, int N) {
  int id = blockIdx.x * 256 + threadIdx.x;
  if (id >= K * N) return;
  int n = id / K, k = id - n * K;
  Wt[id] = (bf16_t)W[(size_t)k * N + n];
}

// ---- embedding gather + cast ----------------------------------------------
__global__ void embed_k(const int* __restrict__ xs, const float* __restrict__ emb,
                        bf16_t* __restrict__ x) {
  int row = blockIdx.x, d = threadIdx.x;
  int tok = xs[row];
  x[(size_t)row * 256 + d] = (bf16_t)emb[(size_t)tok * 256 + d];
}

__global__ void sentinel_k(float* out) { out[0] = 1.0e6f; }

// ---- GEMM: C[M,N] = A[M,K(lda)] * Bt[N,K]^T  (m97 structure) ---------------
// 128x128 tile, BK=32, 256 threads = 4 waves (2x2 of 64x64), global_load_lds.
template <bool F32OUT>
__global__ __launch_bounds__(256) void gemm_bt(
    const bf16_t* __restrict__ A, int lda, const bf16_t* __restrict__ Bt, int K,
    void* __restrict__ Cv, int ldc, const float* __restrict__ bias, int N) {
  __shared__ bf16_t As[128 * 32];
  __shared__ bf16_t Bs[128 * 32];
  const int tid = threadIdx.x;
  const int lane = tid & 63, wave = tid >> 6;
  const int wr = wave >> 1, wc = wave & 1;
  const int lr = lane & 15, lg = lane >> 4;
  const int bm = blockIdx.y, bn = blockIdx.x;

  // staging: each issue = 256 thr x 16B = 64 rows of 32 bf16
  const int ar = tid >> 2;          // row within 64-row half
  const int ac = (tid & 3) * 8;     // elem offset within 32-wide row
  const bf16_t* a0 = A + (size_t)(bm * 128 + ar) * lda + ac;
  const bf16_t* a1 = A + (size_t)(bm * 128 + 64 + ar) * lda + ac;
  int br0 = imin(bn * 128 + ar, N - 1);
  int br1 = imin(bn * 128 + 64 + ar, N - 1);
  const bf16_t* b0 = Bt + (size_t)br0 * K + ac;
  const bf16_t* b1 = Bt + (size_t)br1 * K + ac;
  bf16_t* asd = As + wave * 512;    // wave-uniform LDS dest (elems)
  bf16_t* bsd = Bs + wave * 512;

  f32x4 acc[4][4] = {};
  const int nk = K >> 5;
  for (int kt = 0; kt < nk; ++kt) {
    __syncthreads();
    const int ko = kt * 32;
    GLL16(a0 + ko, asd);
    GLL16(a1 + ko, asd + 2048);
    GLL16(b0 + ko, bsd);
    GLL16(b1 + ko, bsd + 2048);
    asm volatile("s_waitcnt vmcnt(0)" ::: "memory");
    __syncthreads();
    bf16x8 af[4], bfv[4];
#pragma unroll
    for (int m = 0; m < 4; ++m)
      af[m] = *(const bf16x8*)&As[(wr * 64 + m * 16 + lr) * 32 + lg * 8];
#pragma unroll
    for (int n = 0; n < 4; ++n)
      bfv[n] = *(const bf16x8*)&Bs[(wc * 64 + n * 16 + lr) * 32 + lg * 8];
#pragma unroll
    for (int m = 0; m < 4; ++m)
#pragma unroll
      for (int n = 0; n < 4; ++n) acc[m][n] = mfma16(af[m], bfv[n], acc[m][n]);
  }
  // epilogue: D row=(lane>>4)*4+i, col=lane&15  (verified m89/m91 layout)
  const int r0 = bm * 128 + wr * 64;
  const int c0 = bn * 128 + wc * 64;
#pragma unroll
  for (int m = 0; m < 4; ++m)
#pragma unroll
    for (int n = 0; n < 4; ++n) {
      int c = c0 + n * 16 + lr;
      if (c >= N) continue;
#pragma unroll
      for (int i = 0; i < 4; ++i) {
        int r = r0 + m * 16 + lg * 4 + i;
        if (F32OUT)
          ((float*)Cv)[(size_t)r * ldc + c] = acc[m][n][i] + bias[c];
        else
          ((bf16_t*)Cv)[(size_t)r * ldc + c] = (bf16_t)acc[m][n][i];
      }
    }
}

// ---- V transpose: v[b,s,h,dv] -> vt[b,h,dv,s] ------------------------------
__global__ __launch_bounds__(256) void vtrans_k(const bf16_t* __restrict__ v,
                                                bf16_t* __restrict__ vt) {
  __shared__ unsigned short t[64][65];
  const int bh = blockIdx.z, b = bh >> 3, h = bh & 7;
  const int s0 = blockIdx.x * 64, d0 = blockIdx.y * 64;
  const int tid = threadIdx.x;
  const int rr = tid >> 4, cc = (tid & 15) * 4;
  const unsigned short* vv = (const unsigned short*)v;
  unsigned short* vto = (unsigned short*)vt;
#pragma unroll
  for (int it = 0; it < 4; ++it) {
    int s = it * 16 + rr;
    ushort4 x = *(const ushort4*)(vv + (size_t)(b * 1024 + s0 + s) * 2048 +
                                  h * 256 + d0 + cc);
    t[s][cc + 0] = x.x; t[s][cc + 1] = x.y; t[s][cc + 2] = x.z; t[s][cc + 3] = x.w;
  }
  __syncthreads();
#pragma unroll
  for (int it = 0; it < 4; ++it) {
    int d = it * 16 + rr;
    ushort4 w4;
    w4.x = t[cc + 0][d]; w4.y = t[cc + 1][d]; w4.z = t[cc + 2][d]; w4.w = t[cc + 3][d];
    *(ushort4*)(vto + (size_t)((b * 8 + h) * 256 + d0 + d) * 1024 + s0 + cc) = w4;
  }
}

// ---- fused flash attention with relative bias ------------------------------
// VAR: 0 = local (band +-32, 65-entry table), 1 = global (clamp +-128),
//      2 = causal (rel<=0, clamp +-128)
// q,k: [B,S,H*DK] (stride 512), vt: [B,H,DV,S], o: [B,S,H*DV] (stride 2048)
template <int VAR>
__global__ __launch_bounds__(256) void attn_k(
    const bf16_t* __restrict__ q, const bf16_t* __restrict__ kk,
    const bf16_t* __restrict__ vt, const float* __restrict__ bias,
    bf16_t* __restrict__ o) {
  constexpr int S = 1024, H = 8;
  __shared__ bf16_t Klds[64][72];     // +8 pad -> 2-way banks (free)
  __shared__ bf16_t VTlds[256][72];
  __shared__ bf16_t Plds[4][16][72];
  __shared__ float blds[260];
  const int tid = threadIdx.x, lane = tid & 63, w = tid >> 6;
  const int lr = lane & 15, lg = lane >> 4;
  const int qt = blockIdx.x;
  const int bh = blockIdx.y, b = bh >> 3, h = bh & 7;
  const int TSIZE = (VAR == 0) ? 65 : 257;
  for (int t = tid; t < TSIZE; t += 256) blds[t] = bias[t * H + h];
  const int q0 = qt * 64 + w * 16;
  const size_t qrowbase = (size_t)(b * S + q0 + lr) * 512 + h * 64;
  bf16x8 qf0 = *(const bf16x8*)(q + qrowbase + lg * 8);
  bf16x8 qf1 = *(const bf16x8*)(q + qrowbase + 32 + lg * 8);
  f32x4 acc[16] = {};
  float m0[4], l0[4];
#pragma unroll
  for (int i = 0; i < 4; ++i) { m0[i] = -__builtin_inff(); l0[i] = 0.f; }
  int kt0 = 0, kt1 = 15;
  if (VAR == 0) { kt0 = imax(0, (qt * 64 - 32) >> 6); kt1 = imin(15, (qt * 64 + 95) >> 6); }
  if (VAR == 2) { kt1 = qt; }
  const int sr = tid >> 3, sco = (tid & 7) * 8;   // staging coords
  for (int kt = kt0; kt <= kt1; ++kt) {
    __syncthreads();
    // stage K tile [64][64]
#pragma unroll
    for (int it = 0; it < 2; ++it)
      *(bf16x8*)&Klds[it * 32 + sr][sco] =
          *(const bf16x8*)(kk + (size_t)(b * S + kt * 64 + it * 32 + sr) * 512 +
                           h * 64 + sco);
    // stage V^T tile [256][64]
#pragma unroll
    for (int it = 0; it < 8; ++it)
      *(bf16x8*)&VTlds[it * 32 + sr][sco] =
          *(const bf16x8*)(vt + (size_t)((b * H + h) * 256 + it * 32 + sr) * 1024 +
                           kt * 64 + sco);
    __syncthreads();
    // QK^T : S-frags, D row=q (lg*4+i), col=kv (lr)
    f32x4 sf[4];
#pragma unroll
    for (int n = 0; n < 4; ++n) {
      bf16x8 kb0 = *(const bf16x8*)&Klds[n * 16 + lr][lg * 8];
      bf16x8 kb1 = *(const bf16x8*)&Klds[n * 16 + lr][32 + lg * 8];
      f32x4 z = {0.f, 0.f, 0.f, 0.f};
      z = mfma16(qf0, kb0, z);
      z = mfma16(qf1, kb1, z);
      sf[n] = z;
    }
    float tm[4];
#pragma unroll
    for (int i = 0; i < 4; ++i) tm[i] = -__builtin_inff();
#pragma unroll
    for (int n = 0; n < 4; ++n) {
      int kv = kt * 64 + n * 16 + lr;
#pragma unroll
      for (int i = 0; i < 4; ++i) {
        int rel = kv - (q0 + lg * 4 + i);
        float val;
        if (VAR == 0) {
          val = (rel >= -32 && rel <= 32) ? sf[n][i] * 0.125f + blds[rel + 32]
                                          : -1e9f;
        } else if (VAR == 1) {
          int idx = imin(imax(rel, -128), 128) + 128;
          val = sf[n][i] * 0.125f + blds[idx];
        } else {
          int idx = imax(rel, -128) + 128;
          val = (rel <= 0) ? sf[n][i] * 0.125f + blds[idx] : -1e9f;
        }
        sf[n][i] = val;
        tm[i] = fmaxf(tm[i], val);
      }
    }
    // row reduce across the 16 lanes holding this row's 16 kv columns
#pragma unroll
    for (int i = 0; i < 4; ++i)
#pragma unroll
      for (int off = 1; off < 16; off <<= 1)
        tm[i] = fmaxf(tm[i], __shfl_xor(tm[i], off));
    float corr[4], ts[4];
#pragma unroll
    for (int i = 0; i < 4; ++i) {
      float nm = fmaxf(m0[i], tm[i]);
      corr[i] = __expf(m0[i] - nm);
      m0[i] = nm;
      ts[i] = 0.f;
    }
#pragma unroll
    for (int n = 0; n < 4; ++n)
#pragma unroll
      for (int i = 0; i < 4; ++i) {
        float p = __expf(sf[n][i] - m0[i]);
        sf[n][i] = p;
        ts[i] += p;
      }
#pragma unroll
    for (int i = 0; i < 4; ++i) {
#pragma unroll
      for (int off = 1; off < 16; off <<= 1) ts[i] += __shfl_xor(ts[i], off);
      l0[i] = l0[i] * corr[i] + ts[i];
    }
    f32x4 cv = {corr[0], corr[1], corr[2], corr[3]};
#pragma unroll
    for (int nf = 0; nf < 16; ++nf) acc[nf] *= cv;
    // P -> LDS (per-wave buffer; same-wave RAW ordered by compiler)
#pragma unroll
    for (int n = 0; n < 4; ++n)
#pragma unroll
      for (int i = 0; i < 4; ++i)
        Plds[w][lg * 4 + i][n * 16 + lr] = (bf16_t)sf[n][i];
    // PV: A = P[16q x 32kv], B = V[kv x dv] read from V^T tile
#pragma unroll
    for (int c = 0; c < 2; ++c) {
      bf16x8 pa = *(const bf16x8*)&Plds[w][lr][c * 32 + lg * 8];
#pragma unroll
      for (int nf = 0; nf < 16; ++nf) {
        bf16x8 vb = *(const bf16x8*)&VTlds[nf * 16 + lr][c * 32 + lg * 8];
        acc[nf] = mfma16(pa, vb, acc[nf]);
      }
    }
  }
  // epilogue: o[b, q0+lg*4+i, h, nf*16+lr] = acc/l
  float rcp[4];
#pragma unroll
  for (int i = 0; i < 4; ++i) rcp[i] = 1.f / l0[i];
#pragma unroll
  for (int nf = 0; nf < 16; ++nf)
#pragma unroll
    for (int i = 0; i < 4; ++i)
      o[(size_t)(b * S + q0 + lg * 4 + i) * 2048 + h * 256 + nf * 16 + lr] =
          (bf16_t)(acc[nf][i] * rcp[i]);
}

// ---------------------------------------------------------------------------
extern "C" void kernel_launch(void* const* d_in, const int* in_sizes, int n_in,
                              void* d_out, int out_size, void* d_ws,
                              size_t ws_size, hipStream_t stream) {
  const int* xs = (const int*)d_in[0];
  const float* emb = (const float*)d_in[1];
  const float* Wq_l = (const float*)d_in[2];
  const float* Wk_l = (const float*)d_in[3];
  const float* Wv_l = (const float*)d_in[4];
  const float* Wo_l = (const float*)d_in[5];
  const float* bias_l = (const float*)d_in[6];
  const float* Wq_g = (const float*)d_in[7];
  const float* Wk_g = (const float*)d_in[8];
  const float* Wv_g = (const float*)d_in[9];
  const float* Wo_g = (const float*)d_in[10];
  const float* bias_g = (const float*)d_in[11];
  const float* Wq_p = (const float*)d_in[12];
  const float* Wk_p = (const float*)d_in[13];
  const float* Wv_p = (const float*)d_in[14];
  const float* Wo_p = (const float*)d_in[15];
  const float* bias_p = (const float*)d_in[16];
  const float* W_out = (const float*)d_in[17];
  const float* b_out = (const float*)d_in[18];

  char* ws = (char*)d_ws;
  size_t off = 0;
  auto alloc = [&](size_t bytes) -> char* {
    char* p = ws + off;
    off = (off + bytes + 255) & ~(size_t)255;
    return p;
  };
  bf16_t* wq_l_t = (bf16_t*)alloc(512 * 256 * 2);
  bf16_t* wk_l_t = (bf16_t*)alloc(512 * 256 * 2);
  bf16_t* wv_l_t = (bf16_t*)alloc(2048 * 256 * 2);
  bf16_t* wo_l_t = (bf16_t*)alloc(256 * 2048 * 2);
  bf16_t* wq_g_t = (bf16_t*)alloc(512 * 256 * 2);
  bf16_t* wk_g_t = (bf16_t*)alloc(512 * 256 * 2);
  bf16_t* wv_g_t = (bf16_t*)alloc(2048 * 256 * 2);
  bf16_t* wo_g_t = (bf16_t*)alloc(256 * 2048 * 2);
  bf16_t* wq_p_t = (bf16_t*)alloc(512 * 512 * 2);
  bf16_t* wk_p_t = (bf16_t*)alloc(512 * 512 * 2);
  bf16_t* wv_p_t = (bf16_t*)alloc(2048 * 512 * 2);
  bf16_t* wo_p_t = (bf16_t*)alloc(256 * 2048 * 2);
  bf16_t* w_out_t = (bf16_t*)alloc(240 * 256 * 2);
  bf16_t* xb = (bf16_t*)alloc((size_t)8192 * 256 * 2);
  bf16_t* qb = (bf16_t*)alloc((size_t)8192 * 512 * 2);
  bf16_t* kb = (bf16_t*)alloc((size_t)8192 * 512 * 2);
  bf16_t* vb = (bf16_t*)alloc((size_t)8192 * 2048 * 2);   // also attn output
  bf16_t* vtb = (bf16_t*)alloc((size_t)8192 * 2048 * 2);
  bf16_t* h2 = (bf16_t*)alloc((size_t)8192 * 512 * 2);
  bf16_t* h3 = (bf16_t*)alloc((size_t)8192 * 256 * 2);

  if (off > ws_size) {  // diagnosable failure: absmax ~1e6
    sentinel_k<<<1, 1, 0, stream>>>((float*)d_out);
    return;
  }

  auto wc = [&](const float* W, bf16_t* Wt, int K, int N) {
    int tot = K * N;
    wcast_k<<<(tot + 255) / 256, 256, 0, stream>>>(W, Wt, K, N);
  };
  auto gemm = [&](const bf16_t* A, int lda, const bf16_t* Bt, int K, int N,
                  void* C, int ldc, const float* bias) {
    dim3 g((N + 127) / 128, 64);
    if (bias)
      gemm_bt<true><<<g, 256, 0, stream>>>(A, lda, Bt, K, C, ldc, bias, N);
    else
      gemm_bt<false><<<g, 256, 0, stream>>>(A, lda, Bt, K, C, ldc, nullptr, N);
  };

  // weights
  wc(Wq_l, wq_l_t, 256, 512);  wc(Wk_l, wk_l_t, 256, 512);
  wc(Wv_l, wv_l_t, 256, 2048); wc(Wo_l, wo_l_t, 2048, 256);
  wc(Wq_g, wq_g_t, 256, 512);  wc(Wk_g, wk_g_t, 256, 512);
  wc(Wv_g, wv_g_t, 256, 2048); wc(Wo_g, wo_g_t, 2048, 256);
  wc(Wq_p, wq_p_t, 512, 512);  wc(Wk_p, wk_p_t, 512, 512);
  wc(Wv_p, wv_p_t, 512, 2048); wc(Wo_p, wo_p_t, 2048, 256);
  wc(W_out, w_out_t, 256, 240);

  embed_k<<<8192, 256, 0, stream>>>(xs, emb, xb);

  dim3 ag(16, 64), vg(16, 4, 64);
  // local
  gemm(xb, 256, wq_l_t, 256, 512, qb, 512, nullptr);
  gemm(xb, 256, wk_l_t, 256, 512, kb, 512, nullptr);
  gemm(xb, 256, wv_l_t, 256, 2048, vb, 2048, nullptr);
  vtrans_k<<<vg, 256, 0, stream>>>(vb, vtb);
  attn_k<0><<<ag, 256, 0, stream>>>(qb, kb, vtb, bias_l, vb);
  gemm(vb, 2048, wo_l_t, 2048, 256, h2, 512, nullptr);
  // global
  gemm(xb, 256, wq_g_t, 256, 512, qb, 512, nullptr);
  gemm(xb, 256, wk_g_t, 256, 512, kb, 512, nullptr);
  gemm(xb, 256, wv_g_t, 256, 2048, vb, 2048, nullptr);
  vtrans_k<<<vg, 256, 0, stream>>>(vb, vtb);
  attn_k<1><<<ag, 256, 0, stream>>>(qb, kb, vtb, bias_g, vb);
  gemm(vb, 2048, wo_g_t, 2048, 256, h2 + 256, 512, nullptr);
  // predictive (causal) on h2 [8192, 512]
  gemm(h2, 512, wq_p_t, 512, 512, qb, 512, nullptr);
  gemm(h2, 512, wk_p_t, 512, 512, kb, 512, nullptr);
  gemm(h2, 512, wv_p_t, 512, 2048, vb, 2048, nullptr);
  vtrans_k<<<vg, 256, 0, stream>>>(vb, vtb);
  attn_k<2><<<ag, 256, 0, stream>>>(qb, kb, vtb, bias_p, vb);
  gemm(vb, 2048, wo_p_t, 2048, 256, h3, 256, nullptr);
  // head
  gemm(h3, 256, w_out_t, 256, 240, (float*)d_out, 240, b_out);
}

// Round 2
// 595.863 us; speedup vs baseline: 1.2032x; 1.2032x over previous
//
#include <hip/hip_runtime.h>
#include <hip/hip_bf16.h>

// ---------------------------------------------------------------------------
// Model: B=8 S=1024 D=256 H=8 DK=64 DV=256; LB=LF=32, CUT=128, VOCAB=240
// out = head( attn_causal( concat( attn_local(x), attn_global(x) ) ) )
// All matmuls via mfma_f32_16x16x32_bf16 (bf16 in, f32 acc).
// ---------------------------------------------------------------------------

typedef __bf16 bf16_t;
typedef __bf16 bf16x8 __attribute__((ext_vector_type(8)));
typedef float f32x4 __attribute__((ext_vector_type(4)));

__device__ __forceinline__ f32x4 mfma16(bf16x8 a, bf16x8 b, f32x4 c) {
  return __builtin_amdgcn_mfma_f32_16x16x32_bf16(a, b, c, 0, 0, 0);
}

#define GLL16(GP, LP)                                                          \
  __builtin_amdgcn_global_load_lds(                                            \
      (const __attribute__((address_space(1))) void*)(GP),                     \
      (__attribute__((address_space(3))) void*)(LP), 16, 0, 0)

__device__ __forceinline__ int imin(int a, int b) { return a < b ? a : b; }
__device__ __forceinline__ int imax(int a, int b) { return a > b ? a : b; }

// ---- weight transpose + cast: Wt[n*K + k] = (bf16) W[k*N + n] --------------
__global__ void wcast_k(const float* __restrict__ W, bf16_t* __restrict__ Wt,
                        int K, int N) {
  int id = blockIdx.x * 256 + threadIdx.x;
  if (id >= K * N) return;
  int n = id / K, k = id - n * K;
  Wt[id] = (bf16_t)W[(size_t)k * N + n];
}

// ---- embedding gather + cast ----------------------------------------------
__global__ void embed_k(const int* __restrict__ xs, const float* __restrict__ emb,
                        bf16_t* __restrict__ x) {
  int row = blockIdx.x, d = threadIdx.x;
  int tok = xs[row];
  x[(size_t)row * 256 + d] = (bf16_t)emb[(size_t)tok * 256 + d];
}

__global__ void sentinel_k(float* out) { out[0] = 1.0e6f; }

// ---- GEMM 128x128: C[M,N] = A[M,K(lda)] * Bt[N,K]^T  (m97 structure) -------
template <bool F32OUT>
__global__ __launch_bounds__(256) void gemm_bt(
    const bf16_t* __restrict__ A, int lda, const bf16_t* __restrict__ Bt, int K,
    void* __restrict__ Cv, int ldc, const float* __restrict__ bias, int N) {
  __shared__ bf16_t As[128 * 32];
  __shared__ bf16_t Bs[128 * 32];
  const int tid = threadIdx.x;
  const int lane = tid & 63, wave = tid >> 6;
  const int wr = wave >> 1, wc = wave & 1;
  const int lr = lane & 15, lg = lane >> 4;
  const int bm = blockIdx.y, bn = blockIdx.x;

  const int ar = tid >> 2;          // row within 64-row half
  const int ac = (tid & 3) * 8;     // elem offset within 32-wide row
  const bf16_t* a0 = A + (size_t)(bm * 128 + ar) * lda + ac;
  const bf16_t* a1 = A + (size_t)(bm * 128 + 64 + ar) * lda + ac;
  int br0 = imin(bn * 128 + ar, N - 1);
  int br1 = imin(bn * 128 + 64 + ar, N - 1);
  const bf16_t* b0 = Bt + (size_t)br0 * K + ac;
  const bf16_t* b1 = Bt + (size_t)br1 * K + ac;
  bf16_t* asd = As + wave * 512;
  bf16_t* bsd = Bs + wave * 512;

  f32x4 acc[4][4] = {};
  const int nk = K >> 5;
  for (int kt = 0; kt < nk; ++kt) {
    __syncthreads();
    const int ko = kt * 32;
    GLL16(a0 + ko, asd);
    GLL16(a1 + ko, asd + 2048);
    GLL16(b0 + ko, bsd);
    GLL16(b1 + ko, bsd + 2048);
    asm volatile("s_waitcnt vmcnt(0)" ::: "memory");
    __syncthreads();
    bf16x8 af[4], bfv[4];
#pragma unroll
    for (int m = 0; m < 4; ++m)
      af[m] = *(const bf16x8*)&As[(wr * 64 + m * 16 + lr) * 32 + lg * 8];
#pragma unroll
    for (int n = 0; n < 4; ++n)
      bfv[n] = *(const bf16x8*)&Bs[(wc * 64 + n * 16 + lr) * 32 + lg * 8];
#pragma unroll
    for (int m = 0; m < 4; ++m)
#pragma unroll
      for (int n = 0; n < 4; ++n) acc[m][n] = mfma16(af[m], bfv[n], acc[m][n]);
  }
  const int r0 = bm * 128 + wr * 64;
  const int c0 = bn * 128 + wc * 64;
#pragma unroll
  for (int m = 0; m < 4; ++m)
#pragma unroll
    for (int n = 0; n < 4; ++n) {
      int c = c0 + n * 16 + lr;
      if (c >= N) continue;
#pragma unroll
      for (int i = 0; i < 4; ++i) {
        int r = r0 + m * 16 + lg * 4 + i;
        if (F32OUT)
          ((float*)Cv)[(size_t)r * ldc + c] = acc[m][n][i] + bias[c];
        else
          ((bf16_t*)Cv)[(size_t)r * ldc + c] = (bf16_t)acc[m][n][i];
      }
    }
}

// ---- GEMM 64x128 (for small N: more block parallelism) ---------------------
template <bool F32OUT>
__global__ __launch_bounds__(256) void gemm_bt64(
    const bf16_t* __restrict__ A, int lda, const bf16_t* __restrict__ Bt, int K,
    void* __restrict__ Cv, int ldc, const float* __restrict__ bias, int N) {
  __shared__ bf16_t As[64 * 32];
  __shared__ bf16_t Bs[128 * 32];
  const int tid = threadIdx.x;
  const int lane = tid & 63, wave = tid >> 6;
  const int wr = wave >> 1, wc = wave & 1;   // wave tile 32x64
  const int lr = lane & 15, lg = lane >> 4;
  const int bm = blockIdx.y, bn = blockIdx.x;

  const int ar = tid >> 2;
  const int ac = (tid & 3) * 8;
  const bf16_t* a0 = A + (size_t)(bm * 64 + ar) * lda + ac;
  int br0 = imin(bn * 128 + ar, N - 1);
  int br1 = imin(bn * 128 + 64 + ar, N - 1);
  const bf16_t* b0 = Bt + (size_t)br0 * K + ac;
  const bf16_t* b1 = Bt + (size_t)br1 * K + ac;
  bf16_t* asd = As + wave * 512;
  bf16_t* bsd = Bs + wave * 512;

  f32x4 acc[2][4] = {};
  const int nk = K >> 5;
  for (int kt = 0; kt < nk; ++kt) {
    __syncthreads();
    const int ko = kt * 32;
    GLL16(a0 + ko, asd);
    GLL16(b0 + ko, bsd);
    GLL16(b1 + ko, bsd + 2048);
    asm volatile("s_waitcnt vmcnt(0)" ::: "memory");
    __syncthreads();
    bf16x8 af[2], bfv[4];
#pragma unroll
    for (int m = 0; m < 2; ++m)
      af[m] = *(const bf16x8*)&As[(wr * 32 + m * 16 + lr) * 32 + lg * 8];
#pragma unroll
    for (int n = 0; n < 4; ++n)
      bfv[n] = *(const bf16x8*)&Bs[(wc * 64 + n * 16 + lr) * 32 + lg * 8];
#pragma unroll
    for (int m = 0; m < 2; ++m)
#pragma unroll
      for (int n = 0; n < 4; ++n) acc[m][n] = mfma16(af[m], bfv[n], acc[m][n]);
  }
  const int r0 = bm * 64 + wr * 32;
  const int c0 = bn * 128 + wc * 64;
#pragma unroll
  for (int m = 0; m < 2; ++m)
#pragma unroll
    for (int n = 0; n < 4; ++n) {
      int c = c0 + n * 16 + lr;
      if (c >= N) continue;
#pragma unroll
      for (int i = 0; i < 4; ++i) {
        int r = r0 + m * 16 + lg * 4 + i;
        if (F32OUT)
          ((float*)Cv)[(size_t)r * ldc + c] = acc[m][n][i] + bias[c];
        else
          ((bf16_t*)Cv)[(size_t)r * ldc + c] = (bf16_t)acc[m][n][i];
      }
    }
}

// ---- V transpose: v[b,s,h,dv] -> vt[b,h,dv,s] ------------------------------
__global__ __launch_bounds__(256) void vtrans_k(const bf16_t* __restrict__ v,
                                                bf16_t* __restrict__ vt) {
  __shared__ unsigned short t[64][65];
  const int bh = blockIdx.z, b = bh >> 3, h = bh & 7;
  const int s0 = blockIdx.x * 64, d0 = blockIdx.y * 64;
  const int tid = threadIdx.x;
  const int rr = tid >> 4, cc = (tid & 15) * 4;
  const unsigned short* vv = (const unsigned short*)v;
  unsigned short* vto = (unsigned short*)vt;
#pragma unroll
  for (int it = 0; it < 4; ++it) {
    int s = it * 16 + rr;
    ushort4 x = *(const ushort4*)(vv + (size_t)(b * 1024 + s0 + s) * 2048 +
                                  h * 256 + d0 + cc);
    t[s][cc + 0] = x.x; t[s][cc + 1] = x.y; t[s][cc + 2] = x.z; t[s][cc + 3] = x.w;
  }
  __syncthreads();
#pragma unroll
  for (int it = 0; it < 4; ++it) {
    int d = it * 16 + rr;
    ushort4 w4;
    w4.x = t[cc + 0][d]; w4.y = t[cc + 1][d]; w4.z = t[cc + 2][d]; w4.w = t[cc + 3][d];
    *(ushort4*)(vto + (size_t)((b * 8 + h) * 256 + d0 + d) * 1024 + s0 + cc) = w4;
  }
}

// ---- fused flash attention with relative bias ------------------------------
// VAR: 0 = local (band +-32), 1 = global (clamp +-128), 2 = causal
// q,k: [B,S,H*DK] (stride 512), vt: [B,H,DV,S], o: [B,S,H*DV] (stride 2048)
// 512 threads = 8 waves, QBLK=128 (16 q-rows per wave), KVBLK=64.
// K/V^T/P tiles XOR-swizzled: 16B block j at row r lives at j^(r&7).
// K/V staged via global_load_lds (linear LDS dest, pre-swizzled global src).
template <int VAR>
__global__ __launch_bounds__(512) void attn_k(
    const bf16_t* __restrict__ q, const bf16_t* __restrict__ kk,
    const bf16_t* __restrict__ vt, const float* __restrict__ bias,
    bf16_t* __restrict__ o) {
  constexpr int S = 1024, H = 8;
  __shared__ bf16_t Klds[64 * 64];     // 8KB, swizzled
  __shared__ bf16_t VTlds[256 * 64];   // 32KB, swizzled, rows = dv
  __shared__ bf16_t Plds[8 * 16 * 64]; // 16KB, per-wave, swizzled
  __shared__ float blds[260];
  const int tid = threadIdx.x, lane = tid & 63, w = tid >> 6;
  const int lr = lane & 15, lg = lane >> 4;
  const int qt = blockIdx.x;
  const int bh = blockIdx.y, b = bh >> 3, h = bh & 7;
  const int TSIZE = (VAR == 0) ? 65 : 257;
  for (int t = tid; t < TSIZE; t += 512) blds[t] = bias[t * H + h];
  const int q0 = qt * 128 + w * 16;
  const size_t qrowbase = (size_t)(b * S + q0 + lr) * 512 + h * 64;
  bf16x8 qf0 = *(const bf16x8*)(q + qrowbase + lg * 8);
  bf16x8 qf1 = *(const bf16x8*)(q + qrowbase + 32 + lg * 8);
  f32x4 acc[16] = {};
  float m0[4], l0[4];
#pragma unroll
  for (int i = 0; i < 4; ++i) { m0[i] = -__builtin_inff(); l0[i] = 0.f; }
  int kt0 = 0, kt1 = 15;
  if (VAR == 0) {
    kt0 = imax(0, (qt * 128 - 32) >> 6);
    kt1 = imin(15, (qt * 128 + 127 + 32) >> 6);
  }
  if (VAR == 2) kt1 = 2 * qt + 1;
  // staging coords: thread t covers row t>>3, 16B-block t&7 of a [*, 64] tile
  const int sr = tid >> 3, sj = tid & 7;
  const int ksw = (sj ^ (sr & 7)) << 3;     // pre-swizzled source elem offset
  const bf16_t* ksrc = kk + (size_t)(b * S + sr) * 512 + h * 64 + ksw;
  bf16_t* kdst = Klds + w * 512;
  const bf16_t* vsrc0 = vt + (size_t)((b * H + h) * 256 + sr) * 1024 + ksw;
  bf16_t* Pw = Plds + w * 1024;

  for (int kt = kt0; kt <= kt1; ++kt) {
    __syncthreads();
    GLL16(ksrc + (size_t)(kt * 64) * 512, kdst);
#pragma unroll
    for (int qq = 0; qq < 4; ++qq)
      GLL16(vsrc0 + (size_t)(qq * 64) * 1024 + kt * 64, VTlds + qq * 4096 + w * 512);
    asm volatile("s_waitcnt vmcnt(0)" ::: "memory");
    __syncthreads();

    const int kvlo = kt * 64;
    bool active = true;
    if (VAR == 0) active = (kvlo + 63 >= q0 - 32) && (kvlo <= q0 + 47);
    if (VAR == 2) active = (kvlo <= q0 + 15);
    if (active) {
      // QK^T
      f32x4 sf[4];
#pragma unroll
      for (int n = 0; n < 4; ++n) {
        const int R = n * 16 + lr, rs = lr & 7;
        bf16x8 kb0 = *(const bf16x8*)&Klds[R * 64 + ((lg ^ rs) << 3)];
        bf16x8 kb1 = *(const bf16x8*)&Klds[R * 64 + (((4 + lg) ^ rs) << 3)];
        f32x4 z = {0.f, 0.f, 0.f, 0.f};
        z = mfma16(qf0, kb0, z);
        z = mfma16(qf1, kb1, z);
        sf[n] = z;
      }
      float tm[4];
#pragma unroll
      for (int i = 0; i < 4; ++i) tm[i] = -__builtin_inff();
#pragma unroll
      for (int n = 0; n < 4; ++n) {
        int kv = kvlo + n * 16 + lr;
#pragma unroll
        for (int i = 0; i < 4; ++i) {
          int rel = kv - (q0 + lg * 4 + i);
          float val;
          if (VAR == 0) {
            val = (rel >= -32 && rel <= 32) ? sf[n][i] * 0.125f + blds[rel + 32]
                                            : -1e9f;
          } else if (VAR == 1) {
            int idx = imin(imax(rel, -128), 128) + 128;
            val = sf[n][i] * 0.125f + blds[idx];
          } else {
            int idx = imax(rel, -128) + 128;
            val = (rel <= 0) ? sf[n][i] * 0.125f + blds[idx] : -1e9f;
          }
          sf[n][i] = val;
          tm[i] = fmaxf(tm[i], val);
        }
      }
#pragma unroll
      for (int i = 0; i < 4; ++i)
#pragma unroll
        for (int off = 1; off < 16; off <<= 1)
          tm[i] = fmaxf(tm[i], __shfl_xor(tm[i], off));
      // defer-rescale (T13): only rescale when max grew by > 8
      bool need = false;
#pragma unroll
      for (int i = 0; i < 4; ++i) need |= (tm[i] > m0[i] + 8.0f);
      if (__any(need ? 1 : 0)) {
        float corr[4];
#pragma unroll
        for (int i = 0; i < 4; ++i) {
          float nm = fmaxf(m0[i], tm[i]);
          corr[i] = __expf(m0[i] - nm);
          m0[i] = nm;
          l0[i] *= corr[i];
        }
        f32x4 cv = {corr[0], corr[1], corr[2], corr[3]};
#pragma unroll
        for (int nf = 0; nf < 16; ++nf) acc[nf] *= cv;
      }
      float ts[4] = {0.f, 0.f, 0.f, 0.f};
#pragma unroll
      for (int n = 0; n < 4; ++n)
#pragma unroll
        for (int i = 0; i < 4; ++i) {
          float p = __expf(sf[n][i] - m0[i]);
          sf[n][i] = p;
          ts[i] += p;
        }
#pragma unroll
      for (int i = 0; i < 4; ++i) {
#pragma unroll
        for (int off = 1; off < 16; off <<= 1) ts[i] += __shfl_xor(ts[i], off);
        l0[i] += ts[i];
      }
      // P -> per-wave LDS (swizzled)
#pragma unroll
      for (int n = 0; n < 4; ++n)
#pragma unroll
        for (int i = 0; i < 4; ++i) {
          int r = lg * 4 + i, cb = n * 16 + lr;
          Pw[r * 64 + (((cb >> 3) ^ (r & 7)) << 3) + (cb & 7)] =
              (bf16_t)sf[n][i];
        }
      // PV
#pragma unroll
      for (int c = 0; c < 2; ++c) {
        bf16x8 pa = *(const bf16x8*)&Pw[lr * 64 + (((c * 4 + lg) ^ (lr & 7)) << 3)];
#pragma unroll
        for (int nf = 0; nf < 16; ++nf) {
          const int R = nf * 16 + lr;
          bf16x8 vb = *(const bf16x8*)&VTlds[R * 64 + (((c * 4 + lg) ^ (lr & 7)) << 3)];
          acc[nf] = mfma16(pa, vb, acc[nf]);
        }
      }
    }
  }
  float rcp[4];
#pragma unroll
  for (int i = 0; i < 4; ++i) rcp[i] = 1.f / l0[i];
#pragma unroll
  for (int nf = 0; nf < 16; ++nf)
#pragma unroll
    for (int i = 0; i < 4; ++i)
      o[(size_t)(b * S + q0 + lg * 4 + i) * 2048 + h * 256 + nf * 16 + lr] =
          (bf16_t)(acc[nf][i] * rcp[i]);
}

// ---------------------------------------------------------------------------
extern "C" void kernel_launch(void* const* d_in, const int* in_sizes, int n_in,
                              void* d_out, int out_size, void* d_ws,
                              size_t ws_size, hipStream_t stream) {
  const int* xs = (const int*)d_in[0];
  const float* emb = (const float*)d_in[1];
  const float* Wq_l = (const float*)d_in[2];
  const float* Wk_l = (const float*)d_in[3];
  const float* Wv_l = (const float*)d_in[4];
  const float* Wo_l = (const float*)d_in[5];
  const float* bias_l = (const float*)d_in[6];
  const float* Wq_g = (const float*)d_in[7];
  const float* Wk_g = (const float*)d_in[8];
  const float* Wv_g = (const float*)d_in[9];
  const float* Wo_g = (const float*)d_in[10];
  const float* bias_g = (const float*)d_in[11];
  const float* Wq_p = (const float*)d_in[12];
  const float* Wk_p = (const float*)d_in[13];
  const float* Wv_p = (const float*)d_in[14];
  const float* Wo_p = (const float*)d_in[15];
  const float* bias_p = (const float*)d_in[16];
  const float* W_out = (const float*)d_in[17];
  const float* b_out = (const float*)d_in[18];

  char* ws = (char*)d_ws;
  size_t off = 0;
  auto alloc = [&](size_t bytes) -> char* {
    char* p = ws + off;
    off = (off + bytes + 255) & ~(size_t)255;
    return p;
  };
  bf16_t* wq_l_t = (bf16_t*)alloc(512 * 256 * 2);
  bf16_t* wk_l_t = (bf16_t*)alloc(512 * 256 * 2);
  bf16_t* wv_l_t = (bf16_t*)alloc(2048 * 256 * 2);
  bf16_t* wo_l_t = (bf16_t*)alloc(256 * 2048 * 2);
  bf16_t* wq_g_t = (bf16_t*)alloc(512 * 256 * 2);
  bf16_t* wk_g_t = (bf16_t*)alloc(512 * 256 * 2);
  bf16_t* wv_g_t = (bf16_t*)alloc(2048 * 256 * 2);
  bf16_t* wo_g_t = (bf16_t*)alloc(256 * 2048 * 2);
  bf16_t* wq_p_t = (bf16_t*)alloc(512 * 512 * 2);
  bf16_t* wk_p_t = (bf16_t*)alloc(512 * 512 * 2);
  bf16_t* wv_p_t = (bf16_t*)alloc(2048 * 512 * 2);
  bf16_t* wo_p_t = (bf16_t*)alloc(256 * 2048 * 2);
  bf16_t* w_out_t = (bf16_t*)alloc(240 * 256 * 2);
  bf16_t* xb = (bf16_t*)alloc((size_t)8192 * 256 * 2);
  bf16_t* qb = (bf16_t*)alloc((size_t)8192 * 512 * 2);
  bf16_t* kb = (bf16_t*)alloc((size_t)8192 * 512 * 2);
  bf16_t* vb = (bf16_t*)alloc((size_t)8192 * 2048 * 2);   // also attn output
  bf16_t* vtb = (bf16_t*)alloc((size_t)8192 * 2048 * 2);
  bf16_t* h2 = (bf16_t*)alloc((size_t)8192 * 512 * 2);
  bf16_t* h3 = (bf16_t*)alloc((size_t)8192 * 256 * 2);

  if (off > ws_size) {
    sentinel_k<<<1, 1, 0, stream>>>((float*)d_out);
    return;
  }

  auto wc = [&](const float* W, bf16_t* Wt, int K, int N) {
    int tot = K * N;
    wcast_k<<<(tot + 255) / 256, 256, 0, stream>>>(W, Wt, K, N);
  };
  auto gemm = [&](const bf16_t* A, int lda, const bf16_t* Bt, int K, int N,
                  void* C, int ldc, const float* bias) {
    if (N <= 256) {
      dim3 g((N + 127) / 128, 128);
      if (bias)
        gemm_bt64<true><<<g, 256, 0, stream>>>(A, lda, Bt, K, C, ldc, bias, N);
      else
        gemm_bt64<false><<<g, 256, 0, stream>>>(A, lda, Bt, K, C, ldc, nullptr, N);
    } else {
      dim3 g((N + 127) / 128, 64);
      if (bias)
        gemm_bt<true><<<g, 256, 0, stream>>>(A, lda, Bt, K, C, ldc, bias, N);
      else
        gemm_bt<false><<<g, 256, 0, stream>>>(A, lda, Bt, K, C, ldc, nullptr, N);
    }
  };

  // weights
  wc(Wq_l, wq_l_t, 256, 512);  wc(Wk_l, wk_l_t, 256, 512);
  wc(Wv_l, wv_l_t, 256, 2048); wc(Wo_l, wo_l_t, 2048, 256);
  wc(Wq_g, wq_g_t, 256, 512);  wc(Wk_g, wk_g_t, 256, 512);
  wc(Wv_g, wv_g_t, 256, 2048); wc(Wo_g, wo_g_t, 2048, 256);
  wc(Wq_p, wq_p_t, 512, 512);  wc(Wk_p, wk_p_t, 512, 512);
  wc(Wv_p, wv_p_t, 512, 2048); wc(Wo_p, wo_p_t, 2048, 256);
  wc(W_out, w_out_t, 256, 240);

  embed_k<<<8192, 256, 0, stream>>>(xs, emb, xb);

  dim3 ag(8, 64), vg(16, 4, 64);
  // local
  gemm(xb, 256, wq_l_t, 256, 512, qb, 512, nullptr);
  gemm(xb, 256, wk_l_t, 256, 512, kb, 512, nullptr);
  gemm(xb, 256, wv_l_t, 256, 2048, vb, 2048, nullptr);
  vtrans_k<<<vg, 256, 0, stream>>>(vb, vtb);
  attn_k<0><<<ag, 512, 0, stream>>>(qb, kb, vtb, bias_l, vb);
  gemm(vb, 2048, wo_l_t, 2048, 256, h2, 512, nullptr);
  // global
  gemm(xb, 256, wq_g_t, 256, 512, qb, 512, nullptr);
  gemm(xb, 256, wk_g_t, 256, 512, kb, 512, nullptr);
  gemm(xb, 256, wv_g_t, 256, 2048, vb, 2048, nullptr);
  vtrans_k<<<vg, 256, 0, stream>>>(vb, vtb);
  attn_k<1><<<ag, 512, 0, stream>>>(qb, kb, vtb, bias_g, vb);
  gemm(vb, 2048, wo_g_t, 2048, 256, h2 + 256, 512, nullptr);
  // predictive (causal) on h2 [8192, 512]
  gemm(h2, 512, wq_p_t, 512, 512, qb, 512, nullptr);
  gemm(h2, 512, wk_p_t, 512, 512, kb, 512, nullptr);
  gemm(h2, 512, wv_p_t, 512, 2048, vb, 2048, nullptr);
  vtrans_k<<<vg, 256, 0, stream>>>(vb, vtb);
  attn_k<2><<<ag, 512, 0, stream>>>(qb, kb, vtb, bias_p, vb);
  gemm(vb, 2048, wo_p_t, 2048, 256, h3, 256, nullptr);
  // head
  gemm(h3, 256, w_out_t, 256, 240, (float*)d_out, 240, b_out);
}

// Round 3
// 476.455 us; speedup vs baseline: 1.5048x; 1.2506x over previous
//
#include <hip/hip_runtime.h>
#include <hip/hip_bf16.h>

// ---------------------------------------------------------------------------
// Model: B=8 S=1024 D=256 H=8 DK=64 DV=256; LB=LF=32, CUT=128, VOCAB=240
// out = head( attn_causal( concat( attn_local(x), attn_global(x) ) ) )
// All matmuls via mfma_f32_16x16x32_bf16 (bf16 in, f32 acc).
// ---------------------------------------------------------------------------

typedef __bf16 bf16_t;
typedef __bf16 bf16x8 __attribute__((ext_vector_type(8)));
typedef float f32x4 __attribute__((ext_vector_type(4)));

__device__ __forceinline__ f32x4 mfma16(bf16x8 a, bf16x8 b, f32x4 c) {
  return __builtin_amdgcn_mfma_f32_16x16x32_bf16(a, b, c, 0, 0, 0);
}

#define GLL16(GP, LP)                                                          \
  __builtin_amdgcn_global_load_lds(                                            \
      (const __attribute__((address_space(1))) void*)(GP),                     \
      (__attribute__((address_space(3))) void*)(LP), 16, 0, 0)

__device__ __forceinline__ int imin(int a, int b) { return a < b ? a : b; }
__device__ __forceinline__ int imax(int a, int b) { return a > b ? a : b; }

// ---- all weight transposes+casts in one launch -----------------------------
struct WEnt { const float* src; bf16_t* dst; int K; int N; };
struct WPack { WEnt e[13]; };

__global__ void wcast_all(WPack p) {
  const WEnt E = p.e[blockIdx.y];
  const int tot = E.K * E.N;
  for (int id = blockIdx.x * 256 + threadIdx.x; id < tot; id += gridDim.x * 256) {
    int n = id / E.K, k = id - n * E.K;
    E.dst[id] = (bf16_t)E.src[(size_t)k * E.N + n];
  }
}

// ---- embedding gather + cast ----------------------------------------------
__global__ void embed_k(const int* __restrict__ xs, const float* __restrict__ emb,
                        bf16_t* __restrict__ x) {
  int row = blockIdx.x, d = threadIdx.x;
  int tok = xs[row];
  x[(size_t)row * 256 + d] = (bf16_t)emb[(size_t)tok * 256 + d];
}

__global__ void sentinel_k(float* out) { out[0] = 1.0e6f; }

// ---- GEMM 128x128: C[M,N] = A[M,K(lda)] * Bt[N,K]^T  (m97 structure) -------
template <bool F32OUT>
__global__ __launch_bounds__(256) void gemm_bt(
    const bf16_t* __restrict__ A, int lda, const bf16_t* __restrict__ Bt, int K,
    void* __restrict__ Cv, int ldc, const float* __restrict__ bias, int N) {
  __shared__ bf16_t As[128 * 32];
  __shared__ bf16_t Bs[128 * 32];
  const int tid = threadIdx.x;
  const int lane = tid & 63, wave = tid >> 6;
  const int wr = wave >> 1, wc = wave & 1;
  const int lr = lane & 15, lg = lane >> 4;
  const int bm = blockIdx.y, bn = blockIdx.x;

  const int ar = tid >> 2;
  const int ac = (tid & 3) * 8;
  const bf16_t* a0 = A + (size_t)(bm * 128 + ar) * lda + ac;
  const bf16_t* a1 = A + (size_t)(bm * 128 + 64 + ar) * lda + ac;
  int br0 = imin(bn * 128 + ar, N - 1);
  int br1 = imin(bn * 128 + 64 + ar, N - 1);
  const bf16_t* b0 = Bt + (size_t)br0 * K + ac;
  const bf16_t* b1 = Bt + (size_t)br1 * K + ac;
  bf16_t* asd = As + wave * 512;
  bf16_t* bsd = Bs + wave * 512;

  f32x4 acc[4][4] = {};
  const int nk = K >> 5;
  for (int kt = 0; kt < nk; ++kt) {
    __syncthreads();
    const int ko = kt * 32;
    GLL16(a0 + ko, asd);
    GLL16(a1 + ko, asd + 2048);
    GLL16(b0 + ko, bsd);
    GLL16(b1 + ko, bsd + 2048);
    asm volatile("s_waitcnt vmcnt(0)" ::: "memory");
    __syncthreads();
    bf16x8 af[4], bfv[4];
#pragma unroll
    for (int m = 0; m < 4; ++m)
      af[m] = *(const bf16x8*)&As[(wr * 64 + m * 16 + lr) * 32 + lg * 8];
#pragma unroll
    for (int n = 0; n < 4; ++n)
      bfv[n] = *(const bf16x8*)&Bs[(wc * 64 + n * 16 + lr) * 32 + lg * 8];
#pragma unroll
    for (int m = 0; m < 4; ++m)
#pragma unroll
      for (int n = 0; n < 4; ++n) acc[m][n] = mfma16(af[m], bfv[n], acc[m][n]);
  }
  const int r0 = bm * 128 + wr * 64;
  const int c0 = bn * 128 + wc * 64;
#pragma unroll
  for (int m = 0; m < 4; ++m)
#pragma unroll
    for (int n = 0; n < 4; ++n) {
      int c = c0 + n * 16 + lr;
      if (c >= N) continue;
#pragma unroll
      for (int i = 0; i < 4; ++i) {
        int r = r0 + m * 16 + lg * 4 + i;
        if (F32OUT)
          ((float*)Cv)[(size_t)r * ldc + c] = acc[m][n][i] + bias[c];
        else
          ((bf16_t*)Cv)[(size_t)r * ldc + c] = (bf16_t)acc[m][n][i];
      }
    }
}

// ---- GEMM 64x128 (for small N: more block parallelism) ---------------------
template <bool F32OUT>
__global__ __launch_bounds__(256) void gemm_bt64(
    const bf16_t* __restrict__ A, int lda, const bf16_t* __restrict__ Bt, int K,
    void* __restrict__ Cv, int ldc, const float* __restrict__ bias, int N) {
  __shared__ bf16_t As[64 * 32];
  __shared__ bf16_t Bs[128 * 32];
  const int tid = threadIdx.x;
  const int lane = tid & 63, wave = tid >> 6;
  const int wr = wave >> 1, wc = wave & 1;
  const int lr = lane & 15, lg = lane >> 4;
  const int bm = blockIdx.y, bn = blockIdx.x;

  const int ar = tid >> 2;
  const int ac = (tid & 3) * 8;
  const bf16_t* a0 = A + (size_t)(bm * 64 + ar) * lda + ac;
  int br0 = imin(bn * 128 + ar, N - 1);
  int br1 = imin(bn * 128 + 64 + ar, N - 1);
  const bf16_t* b0 = Bt + (size_t)br0 * K + ac;
  const bf16_t* b1 = Bt + (size_t)br1 * K + ac;
  bf16_t* asd = As + wave * 512;
  bf16_t* bsd = Bs + wave * 512;

  f32x4 acc[2][4] = {};
  const int nk = K >> 5;
  for (int kt = 0; kt < nk; ++kt) {
    __syncthreads();
    const int ko = kt * 32;
    GLL16(a0 + ko, asd);
    GLL16(b0 + ko, bsd);
    GLL16(b1 + ko, bsd + 2048);
    asm volatile("s_waitcnt vmcnt(0)" ::: "memory");
    __syncthreads();
    bf16x8 af[2], bfv[4];
#pragma unroll
    for (int m = 0; m < 2; ++m)
      af[m] = *(const bf16x8*)&As[(wr * 32 + m * 16 + lr) * 32 + lg * 8];
#pragma unroll
    for (int n = 0; n < 4; ++n)
      bfv[n] = *(const bf16x8*)&Bs[(wc * 64 + n * 16 + lr) * 32 + lg * 8];
#pragma unroll
    for (int m = 0; m < 2; ++m)
#pragma unroll
      for (int n = 0; n < 4; ++n) acc[m][n] = mfma16(af[m], bfv[n], acc[m][n]);
  }
  const int r0 = bm * 64 + wr * 32;
  const int c0 = bn * 128 + wc * 64;
#pragma unroll
  for (int m = 0; m < 2; ++m)
#pragma unroll
    for (int n = 0; n < 4; ++n) {
      int c = c0 + n * 16 + lr;
      if (c >= N) continue;
#pragma unroll
      for (int i = 0; i < 4; ++i) {
        int r = r0 + m * 16 + lg * 4 + i;
        if (F32OUT)
          ((float*)Cv)[(size_t)r * ldc + c] = acc[m][n][i] + bias[c];
        else
          ((bf16_t*)Cv)[(size_t)r * ldc + c] = (bf16_t)acc[m][n][i];
      }
    }
}

// ---- V transpose: v[b,s,h,dv] (row stride ldv) -> vt[b,h,dv,s] -------------
__global__ __launch_bounds__(256) void vtrans_k(const bf16_t* __restrict__ v,
                                                int ldv,
                                                bf16_t* __restrict__ vt) {
  __shared__ unsigned short t[64][65];
  const int bh = blockIdx.z, b = bh >> 3, h = bh & 7;
  const int s0 = blockIdx.x * 64, d0 = blockIdx.y * 64;
  const int tid = threadIdx.x;
  const int rr = tid >> 4, cc = (tid & 15) * 4;
  const unsigned short* vv = (const unsigned short*)v;
  unsigned short* vto = (unsigned short*)vt;
#pragma unroll
  for (int it = 0; it < 4; ++it) {
    int s = it * 16 + rr;
    ushort4 x = *(const ushort4*)(vv + (size_t)(b * 1024 + s0 + s) * ldv +
                                  h * 256 + d0 + cc);
    t[s][cc + 0] = x.x; t[s][cc + 1] = x.y; t[s][cc + 2] = x.z; t[s][cc + 3] = x.w;
  }
  __syncthreads();
#pragma unroll
  for (int it = 0; it < 4; ++it) {
    int d = it * 16 + rr;
    ushort4 w4;
    w4.x = t[cc + 0][d]; w4.y = t[cc + 1][d]; w4.z = t[cc + 2][d]; w4.w = t[cc + 3][d];
    *(ushort4*)(vto + (size_t)((b * 8 + h) * 256 + d0 + d) * 1024 + s0 + cc) = w4;
  }
}

// ---- fused flash attention with relative bias ------------------------------
// VAR: 0 = local (band +-32), 1 = global (clamp +-128), 2 = causal
// qkv: fused [B,S,3072]: q cols 0..511, k cols 512..1023 (both h*64+dk)
// vt: [B,H,DV,S]; o: output ptr (v-slice), row stride ldo.
// 512 threads = 8 waves, QBLK=128, KVBLK=64, 2-phase dbuf prefetch.
// Grid (bh=64, qt=8) -> XCD = h (L2-local K/V panels).
// VAR==2: wave w owns rows qb0 + j*8 + w (diag-balance); else qb0 + w*16 + j.
template <int VAR>
__global__ __launch_bounds__(512) void attn_k(
    const bf16_t* __restrict__ qkv, const bf16_t* __restrict__ vt,
    const float* __restrict__ bias, bf16_t* __restrict__ o, int ldqk, int ldo) {
  constexpr int S = 1024, H = 8;
  __shared__ bf16_t Klds[2][64 * 64];
  __shared__ bf16_t Vlds[2][256 * 64];
  __shared__ bf16_t Plds[8][16 * 64];
  __shared__ float blds[260];
  const int tid = threadIdx.x, lane = tid & 63, w = tid >> 6;
  const int lr = lane & 15, lg = lane >> 4;
  const int bh = blockIdx.x, qt = blockIdx.y;
  const int b = bh >> 3, h = bh & 7;
  const int TSIZE = (VAR == 0) ? 65 : 257;
  for (int t = tid; t < TSIZE; t += 512) blds[t] = bias[t * H + h];
  const int qb0 = qt * 128;
#define QROW(j) (VAR == 2 ? qb0 + (j) * 8 + w : qb0 + w * 16 + (j))
  const size_t qoff = (size_t)(b * S + QROW(lr)) * ldqk + h * 64;
  bf16x8 qf0 = *(const bf16x8*)(qkv + qoff + lg * 8);
  bf16x8 qf1 = *(const bf16x8*)(qkv + qoff + 32 + lg * 8);
  int qr[4];
#pragma unroll
  for (int i = 0; i < 4; ++i) qr[i] = QROW(lg * 4 + i);

  f32x4 acc[16] = {};
  float m0[4], l0[4];
#pragma unroll
  for (int i = 0; i < 4; ++i) { m0[i] = -__builtin_inff(); l0[i] = 0.f; }
  int kt0 = 0, kt1 = 15;
  if (VAR == 0) {
    kt0 = imax(0, (qb0 - 32) >> 6);
    kt1 = imin(15, (qb0 + 127 + 32) >> 6);
  }
  if (VAR == 2) kt1 = 2 * qt + 1;

  // staging: thread t covers row t>>3, 16B-block t&7; source pre-XOR-swizzled
  const int sr = tid >> 3, sj = tid & 7;
  const int ksw = (sj ^ (sr & 7)) << 3;
  const bf16_t* kbase = qkv + 512 + (size_t)(b * S + sr) * ldqk + h * 64 + ksw;
  const bf16_t* vbase = vt + (size_t)((b * H + h) * 256 + sr) * 1024 + ksw;
  bf16_t* Pw = &Plds[w][0];

  auto STAGE = [&](int kt, int bs) {
    GLL16(kbase + (size_t)(kt * 64) * ldqk, &Klds[bs][w * 512]);
#pragma unroll
    for (int qq = 0; qq < 4; ++qq)
      GLL16(vbase + (size_t)(qq * 64) * 1024 + kt * 64,
            &Vlds[bs][qq * 4096 + w * 512]);
  };

  int cur = 0;
  STAGE(kt0, 0);
  asm volatile("s_waitcnt vmcnt(0)" ::: "memory");
  __syncthreads();

  for (int kt = kt0; kt <= kt1; ++kt) {
    const bool pf = (kt < kt1);
    if (pf) STAGE(kt + 1, cur ^ 1);

    const int kvlo = kt * 64;
    bool active = true;
    if (VAR == 0) {
      int q0w = qb0 + w * 16;
      active = (kvlo + 63 >= q0w - 32) && (kvlo <= q0w + 47);
    }
    if (VAR == 2) active = (kvlo <= qb0 + 120 + w);
    if (active) {
      // QK^T
      f32x4 sf[4];
#pragma unroll
      for (int n = 0; n < 4; ++n) {
        const int R = n * 16 + lr, rs = lr & 7;
        bf16x8 kb0 = *(const bf16x8*)&Klds[cur][R * 64 + ((lg ^ rs) << 3)];
        bf16x8 kb1 = *(const bf16x8*)&Klds[cur][R * 64 + (((4 + lg) ^ rs) << 3)];
        f32x4 z = {0.f, 0.f, 0.f, 0.f};
        z = mfma16(qf0, kb0, z);
        z = mfma16(qf1, kb1, z);
        sf[n] = z;
      }
      float tm[4];
#pragma unroll
      for (int i = 0; i < 4; ++i) tm[i] = -__builtin_inff();
#pragma unroll
      for (int n = 0; n < 4; ++n) {
        int kv = kvlo + n * 16 + lr;
#pragma unroll
        for (int i = 0; i < 4; ++i) {
          int rel = kv - qr[i];
          float val;
          if (VAR == 0) {
            val = (rel >= -32 && rel <= 32) ? sf[n][i] * 0.125f + blds[rel + 32]
                                            : -1e9f;
          } else if (VAR == 1) {
            int idx = imin(imax(rel, -128), 128) + 128;
            val = sf[n][i] * 0.125f + blds[idx];
          } else {
            int idx = imax(rel, -128) + 128;
            val = (rel <= 0) ? sf[n][i] * 0.125f + blds[idx] : -1e9f;
          }
          sf[n][i] = val;
          tm[i] = fmaxf(tm[i], val);
        }
      }
#pragma unroll
      for (int i = 0; i < 4; ++i)
#pragma unroll
        for (int off = 1; off < 16; off <<= 1)
          tm[i] = fmaxf(tm[i], __shfl_xor(tm[i], off));
      // defer-rescale (T13)
      bool need = false;
#pragma unroll
      for (int i = 0; i < 4; ++i) need |= (tm[i] > m0[i] + 8.0f);
      if (__any(need ? 1 : 0)) {
        float corr[4];
#pragma unroll
        for (int i = 0; i < 4; ++i) {
          float nm = fmaxf(m0[i], tm[i]);
          corr[i] = __expf(m0[i] - nm);
          m0[i] = nm;
          l0[i] *= corr[i];
        }
        f32x4 cv = {corr[0], corr[1], corr[2], corr[3]};
#pragma unroll
        for (int nf = 0; nf < 16; ++nf) acc[nf] *= cv;
      }
      float ts[4] = {0.f, 0.f, 0.f, 0.f};
#pragma unroll
      for (int n = 0; n < 4; ++n)
#pragma unroll
        for (int i = 0; i < 4; ++i) {
          float p = __expf(sf[n][i] - m0[i]);
          sf[n][i] = p;
          ts[i] += p;
        }
#pragma unroll
      for (int i = 0; i < 4; ++i) {
#pragma unroll
        for (int off = 1; off < 16; off <<= 1) ts[i] += __shfl_xor(ts[i], off);
        l0[i] += ts[i];
      }
      // P -> per-wave LDS (swizzled)
#pragma unroll
      for (int n = 0; n < 4; ++n)
#pragma unroll
        for (int i = 0; i < 4; ++i) {
          int r = lg * 4 + i, cb = n * 16 + lr;
          Pw[r * 64 + (((cb >> 3) ^ (r & 7)) << 3) + (cb & 7)] =
              (bf16_t)sf[n][i];
        }
      // PV
#pragma unroll
      for (int c = 0; c < 2; ++c) {
        bf16x8 pa = *(const bf16x8*)&Pw[lr * 64 + (((c * 4 + lg) ^ (lr & 7)) << 3)];
#pragma unroll
        for (int nf = 0; nf < 16; ++nf) {
          const int R = nf * 16 + lr;
          bf16x8 vb = *(const bf16x8*)&Vlds[cur][R * 64 + (((c * 4 + lg) ^ (lr & 7)) << 3)];
          acc[nf] = mfma16(pa, vb, acc[nf]);
        }
      }
    }
    if (pf) {
      asm volatile("s_waitcnt vmcnt(0)" ::: "memory");
      __syncthreads();
      cur ^= 1;
    }
  }
  float rcp[4];
#pragma unroll
  for (int i = 0; i < 4; ++i) rcp[i] = 1.f / l0[i];
#pragma unroll
  for (int nf = 0; nf < 16; ++nf)
#pragma unroll
    for (int i = 0; i < 4; ++i)
      o[(size_t)(b * S + qr[i]) * ldo + h * 256 + nf * 16 + lr] =
          (bf16_t)(acc[nf][i] * rcp[i]);
#undef QROW
}

// ---------------------------------------------------------------------------
extern "C" void kernel_launch(void* const* d_in, const int* in_sizes, int n_in,
                              void* d_out, int out_size, void* d_ws,
                              size_t ws_size, hipStream_t stream) {
  const int* xs = (const int*)d_in[0];
  const float* emb = (const float*)d_in[1];
  const float* Wq_l = (const float*)d_in[2];
  const float* Wk_l = (const float*)d_in[3];
  const float* Wv_l = (const float*)d_in[4];
  const float* Wo_l = (const float*)d_in[5];
  const float* bias_l = (const float*)d_in[6];
  const float* Wq_g = (const float*)d_in[7];
  const float* Wk_g = (const float*)d_in[8];
  const float* Wv_g = (const float*)d_in[9];
  const float* Wo_g = (const float*)d_in[10];
  const float* bias_g = (const float*)d_in[11];
  const float* Wq_p = (const float*)d_in[12];
  const float* Wk_p = (const float*)d_in[13];
  const float* Wv_p = (const float*)d_in[14];
  const float* Wo_p = (const float*)d_in[15];
  const float* bias_p = (const float*)d_in[16];
  const float* W_out = (const float*)d_in[17];
  const float* b_out = (const float*)d_in[18];

  char* ws = (char*)d_ws;
  size_t off = 0;
  auto alloc = [&](size_t bytes) -> char* {
    char* p = ws + off;
    off = (off + bytes + 255) & ~(size_t)255;
    return p;
  };
  bf16_t* wqkv_l = (bf16_t*)alloc((size_t)3072 * 256 * 2);
  bf16_t* wqkv_g = (bf16_t*)alloc((size_t)3072 * 256 * 2);
  bf16_t* wqkv_p = (bf16_t*)alloc((size_t)3072 * 512 * 2);
  bf16_t* wo_l_t = (bf16_t*)alloc((size_t)256 * 2048 * 2);
  bf16_t* wo_g_t = (bf16_t*)alloc((size_t)256 * 2048 * 2);
  bf16_t* wo_p_t = (bf16_t*)alloc((size_t)256 * 2048 * 2);
  bf16_t* w_out_t = (bf16_t*)alloc((size_t)240 * 256 * 2);
  bf16_t* xb = (bf16_t*)alloc((size_t)8192 * 256 * 2);
  bf16_t* qkv = (bf16_t*)alloc((size_t)8192 * 3072 * 2);
  bf16_t* vtb = (bf16_t*)alloc((size_t)8192 * 2048 * 2);
  bf16_t* h2 = (bf16_t*)alloc((size_t)8192 * 512 * 2);
  bf16_t* h3 = (bf16_t*)alloc((size_t)8192 * 256 * 2);

  if (off > ws_size) {
    sentinel_k<<<1, 1, 0, stream>>>((float*)d_out);
    return;
  }

  WPack wp;
  wp.e[0] = {Wq_l, wqkv_l, 256, 512};
  wp.e[1] = {Wk_l, wqkv_l + 512 * 256, 256, 512};
  wp.e[2] = {Wv_l, wqkv_l + 1024 * 256, 256, 2048};
  wp.e[3] = {Wq_g, wqkv_g, 256, 512};
  wp.e[4] = {Wk_g, wqkv_g + 512 * 256, 256, 512};
  wp.e[5] = {Wv_g, wqkv_g + 1024 * 256, 256, 2048};
  wp.e[6] = {Wq_p, wqkv_p, 512, 512};
  wp.e[7] = {Wk_p, wqkv_p + 512 * 512, 512, 512};
  wp.e[8] = {Wv_p, wqkv_p + 1024 * 512, 512, 2048};
  wp.e[9] = {Wo_l, wo_l_t, 2048, 256};
  wp.e[10] = {Wo_g, wo_g_t, 2048, 256};
  wp.e[11] = {Wo_p, wo_p_t, 2048, 256};
  wp.e[12] = {W_out, w_out_t, 256, 240};
  wcast_all<<<dim3(512, 13), 256, 0, stream>>>(wp);

  embed_k<<<8192, 256, 0, stream>>>(xs, emb, xb);

  auto gemm_small = [&](const bf16_t* A, int lda, const bf16_t* Bt, int K,
                        int N, void* C, int ldc, const float* bias) {
    dim3 g((N + 127) / 128, 128);
    if (bias)
      gemm_bt64<true><<<g, 256, 0, stream>>>(A, lda, Bt, K, C, ldc, bias, N);
    else
      gemm_bt64<false><<<g, 256, 0, stream>>>(A, lda, Bt, K, C, ldc, nullptr, N);
  };

  dim3 qg(24, 64), ag(64, 8), vg(16, 4, 64);
  // ---- local layer ----
  gemm_bt<false><<<qg, 256, 0, stream>>>(xb, 256, wqkv_l, 256, qkv, 3072,
                                         nullptr, 3072);
  vtrans_k<<<vg, 256, 0, stream>>>(qkv + 1024, 3072, vtb);
  attn_k<0><<<ag, 512, 0, stream>>>(qkv, vtb, bias_l, qkv + 1024, 3072, 3072);
  gemm_small(qkv + 1024, 3072, wo_l_t, 2048, 256, h2, 512, nullptr);
  // ---- global layer ----
  gemm_bt<false><<<qg, 256, 0, stream>>>(xb, 256, wqkv_g, 256, qkv, 3072,
                                         nullptr, 3072);
  vtrans_k<<<vg, 256, 0, stream>>>(qkv + 1024, 3072, vtb);
  attn_k<1><<<ag, 512, 0, stream>>>(qkv, vtb, bias_g, qkv + 1024, 3072, 3072);
  gemm_small(qkv + 1024, 3072, wo_g_t, 2048, 256, h2 + 256, 512, nullptr);
  // ---- predictive (causal) layer on h2 [8192,512] ----
  gemm_bt<false><<<qg, 256, 0, stream>>>(h2, 512, wqkv_p, 512, qkv, 3072,
                                         nullptr, 3072);
  vtrans_k<<<vg, 256, 0, stream>>>(qkv + 1024, 3072, vtb);
  attn_k<2><<<ag, 512, 0, stream>>>(qkv, vtb, bias_p, qkv + 1024, 3072, 3072);
  gemm_small(qkv + 1024, 3072, wo_p_t, 2048, 256, h3, 256, nullptr);
  // ---- head ----
  gemm_small(h3, 256, w_out_t, 256, 240, (float*)d_out, 240, b_out);
}

// Round 4
// 399.689 us; speedup vs baseline: 1.7938x; 1.1921x over previous
//
#include <hip/hip_runtime.h>
#include <hip/hip_bf16.h>

// ---------------------------------------------------------------------------
// Model: B=8 S=1024 D=256 H=8 DK=64 DV=256; LB=LF=32, CUT=128, VOCAB=240
// out = head( attn_causal( concat( attn_local(x), attn_global(x) ) ) )
// All matmuls via mfma_f32_16x16x32_bf16 (bf16 in, f32 acc).
// ---------------------------------------------------------------------------

typedef __bf16 bf16_t;
typedef __bf16 bf16x4 __attribute__((ext_vector_type(4)));
typedef __bf16 bf16x8 __attribute__((ext_vector_type(8)));
typedef float f32x4 __attribute__((ext_vector_type(4)));

__device__ __forceinline__ f32x4 mfma16(bf16x8 a, bf16x8 b, f32x4 c) {
  return __builtin_amdgcn_mfma_f32_16x16x32_bf16(a, b, c, 0, 0, 0);
}

#define GLL16(GP, LP)                                                          \
  __builtin_amdgcn_global_load_lds(                                            \
      (const __attribute__((address_space(1))) void*)(GP),                     \
      (__attribute__((address_space(3))) void*)(LP), 16, 0, 0)

__device__ __forceinline__ int imin(int a, int b) { return a < b ? a : b; }
__device__ __forceinline__ int imax(int a, int b) { return a > b ? a : b; }

// ---- all weight transposes+casts in one launch -----------------------------
struct WEnt { const float* src; bf16_t* dst; int K; int N; };
struct WPack { WEnt e[13]; };

__global__ void wcast_all(WPack p) {
  const WEnt E = p.e[blockIdx.y];
  const int tot = E.K * E.N;
  for (int id = blockIdx.x * 256 + threadIdx.x; id < tot; id += gridDim.x * 256) {
    int n = id / E.K, k = id - n * E.K;
    E.dst[id] = (bf16_t)E.src[(size_t)k * E.N + n];
  }
}

// ---- embedding gather + cast ----------------------------------------------
__global__ void embed_k(const int* __restrict__ xs, const float* __restrict__ emb,
                        bf16_t* __restrict__ x) {
  int row = blockIdx.x, d = threadIdx.x;
  int tok = xs[row];
  x[(size_t)row * 256 + d] = (bf16_t)emb[(size_t)tok * 256 + d];
}

__global__ void sentinel_k(float* out) { out[0] = 1.0e6f; }

// ---- GEMM 128x128, 2-phase dbuf: C = A[M,K] * Bt[N,K]^T --------------------
// VT mode: columns c>=1024 (v-slice of fused qkv) are written TRANSPOSED into
// vt[b*2048 + (c-1024)][s] instead of C (fuses the V transpose).
template <bool F32OUT, bool VT>
__global__ __launch_bounds__(256) void gemm_bt(
    const bf16_t* __restrict__ A, int lda, const bf16_t* __restrict__ Bt, int K,
    void* __restrict__ Cv, int ldc, const float* __restrict__ bias, int N,
    bf16_t* __restrict__ vt) {
  __shared__ bf16_t As[2][128 * 32];
  __shared__ bf16_t Bs[2][128 * 32];
  const int tid = threadIdx.x;
  const int lane = tid & 63, wave = tid >> 6;
  const int wr = wave >> 1, wc = wave & 1;
  const int lr = lane & 15, lg = lane >> 4;
  const int bm = blockIdx.y, bn = blockIdx.x;

  const int ar = tid >> 2;
  const int ac = (tid & 3) * 8;
  const bf16_t* a0 = A + (size_t)(bm * 128 + ar) * lda + ac;
  const bf16_t* a1 = A + (size_t)(bm * 128 + 64 + ar) * lda + ac;
  int br0 = imin(bn * 128 + ar, N - 1);
  int br1 = imin(bn * 128 + 64 + ar, N - 1);
  const bf16_t* b0 = Bt + (size_t)br0 * K + ac;
  const bf16_t* b1 = Bt + (size_t)br1 * K + ac;

  f32x4 acc[4][4] = {};
  const int nk = K >> 5;

  auto STAGE = [&](int kt, int bs) {
    const int ko = kt * 32;
    GLL16(a0 + ko, &As[bs][wave * 512]);
    GLL16(a1 + ko, &As[bs][2048 + wave * 512]);
    GLL16(b0 + ko, &Bs[bs][wave * 512]);
    GLL16(b1 + ko, &Bs[bs][2048 + wave * 512]);
  };

  STAGE(0, 0);
  asm volatile("s_waitcnt vmcnt(0)" ::: "memory");
  __syncthreads();
  int cur = 0;
  for (int kt = 0; kt < nk; ++kt) {
    const bool pf = (kt + 1 < nk);
    if (pf) STAGE(kt + 1, cur ^ 1);
    bf16x8 af[4], bfv[4];
#pragma unroll
    for (int m = 0; m < 4; ++m)
      af[m] = *(const bf16x8*)&As[cur][(wr * 64 + m * 16 + lr) * 32 + lg * 8];
#pragma unroll
    for (int n = 0; n < 4; ++n)
      bfv[n] = *(const bf16x8*)&Bs[cur][(wc * 64 + n * 16 + lr) * 32 + lg * 8];
#pragma unroll
    for (int m = 0; m < 4; ++m)
#pragma unroll
      for (int n = 0; n < 4; ++n) acc[m][n] = mfma16(af[m], bfv[n], acc[m][n]);
    if (pf) {
      asm volatile("s_waitcnt vmcnt(0)" ::: "memory");
      __syncthreads();
      cur ^= 1;
    }
  }
  const int r0 = bm * 128 + wr * 64;
  const int c0 = bn * 128 + wc * 64;
  if (VT && c0 >= 1024) {
    // v-slice: write transposed into vt[(b*2048 + c-1024)][s]
    const int bq = r0 >> 10;
    const int s0 = r0 & 1023;
#pragma unroll
    for (int m = 0; m < 4; ++m)
#pragma unroll
      for (int n = 0; n < 4; ++n) {
        int c = c0 + n * 16 + lr;
        bf16x4 pk;
#pragma unroll
        for (int i = 0; i < 4; ++i) pk[i] = (bf16_t)acc[m][n][i];
        *(bf16x4*)(vt + (size_t)(bq * 2048 + (c - 1024)) * 1024 + s0 + m * 16 +
                   lg * 4) = pk;
      }
  } else {
#pragma unroll
    for (int m = 0; m < 4; ++m)
#pragma unroll
      for (int n = 0; n < 4; ++n) {
        int c = c0 + n * 16 + lr;
        if (c >= N) continue;
#pragma unroll
        for (int i = 0; i < 4; ++i) {
          int r = r0 + m * 16 + lg * 4 + i;
          if (F32OUT)
            ((float*)Cv)[(size_t)r * ldc + c] = acc[m][n][i] + bias[c];
          else
            ((bf16_t*)Cv)[(size_t)r * ldc + c] = (bf16_t)acc[m][n][i];
        }
      }
  }
}

// ---- GEMM 64x128, 2-phase dbuf (small N: more block parallelism) -----------
template <bool F32OUT>
__global__ __launch_bounds__(256) void gemm_bt64(
    const bf16_t* __restrict__ A, int lda, const bf16_t* __restrict__ Bt, int K,
    void* __restrict__ Cv, int ldc, const float* __restrict__ bias, int N) {
  __shared__ bf16_t As[2][64 * 32];
  __shared__ bf16_t Bs[2][128 * 32];
  const int tid = threadIdx.x;
  const int lane = tid & 63, wave = tid >> 6;
  const int wr = wave >> 1, wc = wave & 1;
  const int lr = lane & 15, lg = lane >> 4;
  const int bm = blockIdx.y, bn = blockIdx.x;

  const int ar = tid >> 2;
  const int ac = (tid & 3) * 8;
  const bf16_t* a0 = A + (size_t)(bm * 64 + ar) * lda + ac;
  int br0 = imin(bn * 128 + ar, N - 1);
  int br1 = imin(bn * 128 + 64 + ar, N - 1);
  const bf16_t* b0 = Bt + (size_t)br0 * K + ac;
  const bf16_t* b1 = Bt + (size_t)br1 * K + ac;

  f32x4 acc[2][4] = {};
  const int nk = K >> 5;

  auto STAGE = [&](int kt, int bs) {
    const int ko = kt * 32;
    GLL16(a0 + ko, &As[bs][wave * 512]);
    GLL16(b0 + ko, &Bs[bs][wave * 512]);
    GLL16(b1 + ko, &Bs[bs][2048 + wave * 512]);
  };

  STAGE(0, 0);
  asm volatile("s_waitcnt vmcnt(0)" ::: "memory");
  __syncthreads();
  int cur = 0;
  for (int kt = 0; kt < nk; ++kt) {
    const bool pf = (kt + 1 < nk);
    if (pf) STAGE(kt + 1, cur ^ 1);
    bf16x8 af[2], bfv[4];
#pragma unroll
    for (int m = 0; m < 2; ++m)
      af[m] = *(const bf16x8*)&As[cur][(wr * 32 + m * 16 + lr) * 32 + lg * 8];
#pragma unroll
    for (int n = 0; n < 4; ++n)
      bfv[n] = *(const bf16x8*)&Bs[cur][(wc * 64 + n * 16 + lr) * 32 + lg * 8];
#pragma unroll
    for (int m = 0; m < 2; ++m)
#pragma unroll
      for (int n = 0; n < 4; ++n) acc[m][n] = mfma16(af[m], bfv[n], acc[m][n]);
    if (pf) {
      asm volatile("s_waitcnt vmcnt(0)" ::: "memory");
      __syncthreads();
      cur ^= 1;
    }
  }
  const int r0 = bm * 64 + wr * 32;
  const int c0 = bn * 128 + wc * 64;
#pragma unroll
  for (int m = 0; m < 2; ++m)
#pragma unroll
    for (int n = 0; n < 4; ++n) {
      int c = c0 + n * 16 + lr;
      if (c >= N) continue;
#pragma unroll
      for (int i = 0; i < 4; ++i) {
        int r = r0 + m * 16 + lg * 4 + i;
        if (F32OUT)
          ((float*)Cv)[(size_t)r * ldc + c] = acc[m][n][i] + bias[c];
        else
          ((bf16_t*)Cv)[(size_t)r * ldc + c] = (bf16_t)acc[m][n][i];
      }
    }
}

// ---- fused flash attention with relative bias ------------------------------
// VAR: 0 = local (band +-32), 1 = global (clamp +-128), 2 = causal
// qkv: fused [B,S,3072]: q cols 0..511, k cols 512..1023 (both h*64+dk)
// vt: [B,H,DV,S]; o: output ptr (v-slice), row stride ldo.
// 512 threads = 8 waves, QBLK=128, KVBLK=64, 2-phase dbuf prefetch.
// Grid (bh=64, qt=8) -> XCD = h (L2-local K/V panels).
// VAR==2: wave w owns rows qb0 + j*8 + w (diag-balance); else qb0 + w*16 + j.
// Softmax: per-lane max/sum; cross-lane max only on (rare) rescale; l-sum
// reduced once at the end. Saturated-bias tiles use fma-only fast path.
template <int VAR>
__global__ __launch_bounds__(512) void attn_k(
    const bf16_t* __restrict__ qkv, const bf16_t* __restrict__ vt,
    const float* __restrict__ bias, bf16_t* __restrict__ o, int ldqk, int ldo) {
  constexpr int S = 1024, H = 8;
  __shared__ bf16_t Klds[2][64 * 64];
  __shared__ bf16_t Vlds[2][256 * 64];
  __shared__ bf16_t Plds[8][16 * 64];
  __shared__ float blds[260];
  const int tid = threadIdx.x, lane = tid & 63, w = tid >> 6;
  const int lr = lane & 15, lg = lane >> 4;
  const int bh = blockIdx.x, qt = blockIdx.y;
  const int b = bh >> 3, h = bh & 7;
  const int TSIZE = (VAR == 0) ? 65 : 257;
  for (int t = tid; t < TSIZE; t += 512) blds[t] = bias[t * H + h];
  const int qb0 = qt * 128;
#define QROW(j) (VAR == 2 ? qb0 + (j) * 8 + w : qb0 + w * 16 + (j))
  const size_t qoff = (size_t)(b * S + QROW(lr)) * ldqk + h * 64;
  bf16x8 qf0 = *(const bf16x8*)(qkv + qoff + lg * 8);
  bf16x8 qf1 = *(const bf16x8*)(qkv + qoff + 32 + lg * 8);
  int qr[4];
#pragma unroll
  for (int i = 0; i < 4; ++i) qr[i] = QROW(lg * 4 + i);

  f32x4 acc[16] = {};
  float m0[4], l0[4];
#pragma unroll
  for (int i = 0; i < 4; ++i) { m0[i] = -__builtin_inff(); l0[i] = 0.f; }
  int kt0 = 0, kt1 = 15;
  if (VAR == 0) {
    kt0 = imax(0, (qb0 - 32) >> 6);
    kt1 = imin(15, (qb0 + 127 + 32) >> 6);
  }
  if (VAR == 2) kt1 = 2 * qt + 1;

  const int sr = tid >> 3, sj = tid & 7;
  const int ksw = (sj ^ (sr & 7)) << 3;
  const bf16_t* kbase = qkv + 512 + (size_t)(b * S + sr) * ldqk + h * 64 + ksw;
  const bf16_t* vbase = vt + (size_t)((b * H + h) * 256 + sr) * 1024 + ksw;
  bf16_t* Pw = &Plds[w][0];

  auto STAGE = [&](int kt, int bs) {
    GLL16(kbase + (size_t)(kt * 64) * ldqk, &Klds[bs][w * 512]);
#pragma unroll
    for (int qq = 0; qq < 4; ++qq)
      GLL16(vbase + (size_t)(qq * 64) * 1024 + kt * 64,
            &Vlds[bs][qq * 4096 + w * 512]);
  };

  int cur = 0;
  STAGE(kt0, 0);
  asm volatile("s_waitcnt vmcnt(0)" ::: "memory");
  __syncthreads();

  for (int kt = kt0; kt <= kt1; ++kt) {
    const bool pf = (kt < kt1);
    if (pf) STAGE(kt + 1, cur ^ 1);

    const int kvlo = kt * 64;
    bool active = true;
    if (VAR == 0) {
      int q0w = qb0 + w * 16;
      active = (kvlo + 63 >= q0w - 32) && (kvlo <= q0w + 47);
    }
    if (VAR == 2) active = (kvlo <= qb0 + 120 + w);
    if (active) {
      // QK^T
      f32x4 sf[4];
#pragma unroll
      for (int n = 0; n < 4; ++n) {
        const int R = n * 16 + lr, rs = lr & 7;
        bf16x8 kb0 = *(const bf16x8*)&Klds[cur][R * 64 + ((lg ^ rs) << 3)];
        bf16x8 kb1 = *(const bf16x8*)&Klds[cur][R * 64 + (((4 + lg) ^ rs) << 3)];
        f32x4 z = {0.f, 0.f, 0.f, 0.f};
        z = mfma16(qf0, kb0, z);
        z = mfma16(qf1, kb1, z);
        sf[n] = z;
      }
      // bias/mask; per-lane max only
      bool sat = false;
      float cb = 0.f;
      if (VAR == 1) {
        if (kvlo + 63 <= qb0 - 128) { sat = true; cb = blds[0]; }
        else if (kvlo >= qb0 + 255) { sat = true; cb = blds[256]; }
      } else if (VAR == 2) {
        if (kvlo + 63 <= qb0 - 128) { sat = true; cb = blds[0]; }
      }
      float tmL[4];
#pragma unroll
      for (int i = 0; i < 4; ++i) tmL[i] = -__builtin_inff();
      if (sat) {
#pragma unroll
        for (int n = 0; n < 4; ++n)
#pragma unroll
          for (int i = 0; i < 4; ++i) {
            float val = sf[n][i] * 0.125f + cb;
            sf[n][i] = val;
            tmL[i] = fmaxf(tmL[i], val);
          }
      } else {
#pragma unroll
        for (int n = 0; n < 4; ++n) {
          int kv = kvlo + n * 16 + lr;
#pragma unroll
          for (int i = 0; i < 4; ++i) {
            int rel = kv - qr[i];
            float val;
            if (VAR == 0) {
              val = (rel >= -32 && rel <= 32)
                        ? sf[n][i] * 0.125f + blds[rel + 32] : -1e9f;
            } else if (VAR == 1) {
              int idx = imin(imax(rel, -128), 128) + 128;
              val = sf[n][i] * 0.125f + blds[idx];
            } else {
              int idx = imax(rel, -128) + 128;
              val = (rel <= 0) ? sf[n][i] * 0.125f + blds[idx] : -1e9f;
            }
            sf[n][i] = val;
            tmL[i] = fmaxf(tmL[i], val);
          }
        }
      }
      // deferred rescale: cross-lane max only when some lane exceeds m0+8
      bool need = false;
#pragma unroll
      for (int i = 0; i < 4; ++i) need |= (tmL[i] > m0[i] + 8.0f);
      if (__any(need ? 1 : 0)) {
        float corr[4];
#pragma unroll
        for (int i = 0; i < 4; ++i) {
          float tm = tmL[i];
#pragma unroll
          for (int off = 1; off < 16; off <<= 1)
            tm = fmaxf(tm, __shfl_xor(tm, off));
          float nm = fmaxf(m0[i], tm);
          corr[i] = __expf(m0[i] - nm);
          m0[i] = nm;
          l0[i] *= corr[i];
        }
        f32x4 cv = {corr[0], corr[1], corr[2], corr[3]};
#pragma unroll
        for (int nf = 0; nf < 16; ++nf) acc[nf] *= cv;
      }
#pragma unroll
      for (int n = 0; n < 4; ++n)
#pragma unroll
        for (int i = 0; i < 4; ++i) {
          float p = __expf(sf[n][i] - m0[i]);
          sf[n][i] = p;
          l0[i] += p;           // per-lane partial; reduced at the end
        }
      // P -> per-wave LDS (swizzled)
#pragma unroll
      for (int n = 0; n < 4; ++n)
#pragma unroll
        for (int i = 0; i < 4; ++i) {
          int r = lg * 4 + i, cb2 = n * 16 + lr;
          Pw[r * 64 + (((cb2 >> 3) ^ (r & 7)) << 3) + (cb2 & 7)] =
              (bf16_t)sf[n][i];
        }
      // PV
#pragma unroll
      for (int c = 0; c < 2; ++c) {
        bf16x8 pa = *(const bf16x8*)&Pw[lr * 64 + (((c * 4 + lg) ^ (lr & 7)) << 3)];
#pragma unroll
        for (int nf = 0; nf < 16; ++nf) {
          const int R = nf * 16 + lr;
          bf16x8 vb = *(const bf16x8*)&Vlds[cur][R * 64 + (((c * 4 + lg) ^ (lr & 7)) << 3)];
          acc[nf] = mfma16(pa, vb, acc[nf]);
        }
      }
    }
    if (pf) {
      asm volatile("s_waitcnt vmcnt(0)" ::: "memory");
      __syncthreads();
      cur ^= 1;
    }
  }
  // final cross-lane l reduction, then scale+store
  float rcp[4];
#pragma unroll
  for (int i = 0; i < 4; ++i) {
    float l = l0[i];
#pragma unroll
    for (int off = 1; off < 16; off <<= 1) l += __shfl_xor(l, off);
    rcp[i] = 1.f / l;
  }
#pragma unroll
  for (int nf = 0; nf < 16; ++nf)
#pragma unroll
    for (int i = 0; i < 4; ++i)
      o[(size_t)(b * S + qr[i]) * ldo + h * 256 + nf * 16 + lr] =
          (bf16_t)(acc[nf][i] * rcp[i]);
#undef QROW
}

// ---------------------------------------------------------------------------
extern "C" void kernel_launch(void* const* d_in, const int* in_sizes, int n_in,
                              void* d_out, int out_size, void* d_ws,
                              size_t ws_size, hipStream_t stream) {
  const int* xs = (const int*)d_in[0];
  const float* emb = (const float*)d_in[1];
  const float* Wq_l = (const float*)d_in[2];
  const float* Wk_l = (const float*)d_in[3];
  const float* Wv_l = (const float*)d_in[4];
  const float* Wo_l = (const float*)d_in[5];
  const float* bias_l = (const float*)d_in[6];
  const float* Wq_g = (const float*)d_in[7];
  const float* Wk_g = (const float*)d_in[8];
  const float* Wv_g = (const float*)d_in[9];
  const float* Wo_g = (const float*)d_in[10];
  const float* bias_g = (const float*)d_in[11];
  const float* Wq_p = (const float*)d_in[12];
  const float* Wk_p = (const float*)d_in[13];
  const float* Wv_p = (const float*)d_in[14];
  const float* Wo_p = (const float*)d_in[15];
  const float* bias_p = (const float*)d_in[16];
  const float* W_out = (const float*)d_in[17];
  const float* b_out = (const float*)d_in[18];

  char* ws = (char*)d_ws;
  size_t off = 0;
  auto alloc = [&](size_t bytes) -> char* {
    char* p = ws + off;
    off = (off + bytes + 255) & ~(size_t)255;
    return p;
  };
  bf16_t* wqkv_l = (bf16_t*)alloc((size_t)3072 * 256 * 2);
  bf16_t* wqkv_g = (bf16_t*)alloc((size_t)3072 * 256 * 2);
  bf16_t* wqkv_p = (bf16_t*)alloc((size_t)3072 * 512 * 2);
  bf16_t* wo_l_t = (bf16_t*)alloc((size_t)256 * 2048 * 2);
  bf16_t* wo_g_t = (bf16_t*)alloc((size_t)256 * 2048 * 2);
  bf16_t* wo_p_t = (bf16_t*)alloc((size_t)256 * 2048 * 2);
  bf16_t* w_out_t = (bf16_t*)alloc((size_t)240 * 256 * 2);
  bf16_t* xb = (bf16_t*)alloc((size_t)8192 * 256 * 2);
  bf16_t* qkv = (bf16_t*)alloc((size_t)8192 * 3072 * 2);
  bf16_t* vtb = (bf16_t*)alloc((size_t)8192 * 2048 * 2);
  bf16_t* h2 = (bf16_t*)alloc((size_t)8192 * 512 * 2);
  bf16_t* h3 = (bf16_t*)alloc((size_t)8192 * 256 * 2);

  if (off > ws_size) {
    sentinel_k<<<1, 1, 0, stream>>>((float*)d_out);
    return;
  }

  WPack wp;
  wp.e[0] = {Wq_l, wqkv_l, 256, 512};
  wp.e[1] = {Wk_l, wqkv_l + 512 * 256, 256, 512};
  wp.e[2] = {Wv_l, wqkv_l + 1024 * 256, 256, 2048};
  wp.e[3] = {Wq_g, wqkv_g, 256, 512};
  wp.e[4] = {Wk_g, wqkv_g + 512 * 256, 256, 512};
  wp.e[5] = {Wv_g, wqkv_g + 1024 * 256, 256, 2048};
  wp.e[6] = {Wq_p, wqkv_p, 512, 512};
  wp.e[7] = {Wk_p, wqkv_p + 512 * 512, 512, 512};
  wp.e[8] = {Wv_p, wqkv_p + 1024 * 512, 512, 2048};
  wp.e[9] = {Wo_l, wo_l_t, 2048, 256};
  wp.e[10] = {Wo_g, wo_g_t, 2048, 256};
  wp.e[11] = {Wo_p, wo_p_t, 2048, 256};
  wp.e[12] = {W_out, w_out_t, 256, 240};
  wcast_all<<<dim3(512, 13), 256, 0, stream>>>(wp);

  embed_k<<<8192, 256, 0, stream>>>(xs, emb, xb);

  auto gemm_small = [&](const bf16_t* A, int lda, const bf16_t* Bt, int K,
                        int N, void* C, int ldc, const float* bias) {
    dim3 g((N + 127) / 128, 128);
    if (bias)
      gemm_bt64<true><<<g, 256, 0, stream>>>(A, lda, Bt, K, C, ldc, bias, N);
    else
      gemm_bt64<false><<<g, 256, 0, stream>>>(A, lda, Bt, K, C, ldc, nullptr, N);
  };

  dim3 qg(24, 64), ag(64, 8);
  // ---- local layer ----
  gemm_bt<false, true><<<qg, 256, 0, stream>>>(xb, 256, wqkv_l, 256, qkv, 3072,
                                               nullptr, 3072, vtb);
  attn_k<0><<<ag, 512, 0, stream>>>(qkv, vtb, bias_l, qkv + 1024, 3072, 3072);
  gemm_small(qkv + 1024, 3072, wo_l_t, 2048, 256, h2, 512, nullptr);
  // ---- global layer ----
  gemm_bt<false, true><<<qg, 256, 0, stream>>>(xb, 256, wqkv_g, 256, qkv, 3072,
                                               nullptr, 3072, vtb);
  attn_k<1><<<ag, 512, 0, stream>>>(qkv, vtb, bias_g, qkv + 1024, 3072, 3072);
  gemm_small(qkv + 1024, 3072, wo_g_t, 2048, 256, h2 + 256, 512, nullptr);
  // ---- predictive (causal) layer on h2 [8192,512] ----
  gemm_bt<false, true><<<qg, 256, 0, stream>>>(h2, 512, wqkv_p, 512, qkv, 3072,
                                               nullptr, 3072, vtb);
  attn_k<2><<<ag, 512, 0, stream>>>(qkv, vtb, bias_p, qkv + 1024, 3072, 3072);
  gemm_small(qkv + 1024, 3072, wo_p_t, 2048, 256, h3, 256, nullptr);
  // ---- head ----
  gemm_small(h3, 256, w_out_t, 256, 240, (float*)d_out, 240, b_out);
}